// Round 7
// baseline (336.617 us; speedup 1.0000x reference)
//
#include <hip/hip_runtime.h>

// GTCNN fused persistent kernel.
// Math (verified rounds 2-4): Adj = s0 I + s1 (I⊗As) + s2 (At⊗I) + s3 (At⊗As)
//   => per layer: w = temporal mix (At over t);  u = s1 h + s3 w;  p = s0 h + s2 w
//      Ah = p + As ⊛ u (spatial over n);  h' = tanh(Ah @ Hsum[l]),  Hsum = Σ_k H[l,k]
// Shapes: B=2, T=64, N=128, F=32, out F=16.
//
// Single kernel, 256 blocks (=CU count; 110KB LDS -> 1 block/CU => co-resident),
// 3 device-scope grid barriers between the 4 phases:
//   A: proj(x@W1+b1) + temporal L0   (block role (b,n))
//   B: spatial + filter L0           (block role (b,t,mh))
//   C: temporal L1                   (block role (b,n))
//   D: spatial + filter L1 + out-proj(W2,b2)
//
// Barrier counter is memset to 0 on the stream each call (graph-capturable,
// deterministic across replays); targets are explicit phase*NBLK.
// All lane-distinct LDS tiles use the XOR group swizzle g' = g ^ (row&7):
// bank-set = (g&7)^(row&7) covers all 8 sets evenly for every access pattern.

#define NBLK 256

__device__ __forceinline__ int swz(int row, int g) { return g ^ (row & 7); }

// Grid barrier: counter starts at 0 (host memset); phase p waits for p*NBLK.
// Bounded spin: degrades to wrong-output (diagnosable) instead of hang if
// co-residency were ever violated; never triggers in normal operation.
__device__ __forceinline__ void gbar(unsigned* cnt, unsigned tgt) {
    __syncthreads();
    __threadfence();                                   // release my block's writes
    if (threadIdx.x == 0) {
        __hip_atomic_fetch_add(cnt, 1u, __ATOMIC_RELEASE, __HIP_MEMORY_SCOPE_AGENT);
        int guard = 1 << 24;
        while (__hip_atomic_load(cnt, __ATOMIC_ACQUIRE,
                                 __HIP_MEMORY_SCOPE_AGENT) < tgt && --guard)
            __builtin_amdgcn_s_sleep(2);
    }
    __syncthreads();
    __threadfence();                                   // acquire side
}

__global__ __launch_bounds__(512) void k_fused(
    const float* __restrict__ x,  const float* __restrict__ At,
    const float* __restrict__ As, const float* __restrict__ s,
    const float* __restrict__ H,  const float* __restrict__ W1,
    const float* __restrict__ b1, const float* __restrict__ W2,
    const float* __restrict__ b2,
    float* __restrict__ up, float* __restrict__ pp, float* __restrict__ hbuf,
    unsigned* __restrict__ barcnt, float* __restrict__ out)
{
    __shared__ float As_s[64 * 128];  // 32KB  half-tile rows As[mh*64 + r], swizzled
    __shared__ float At_s[64 * 64];   // 16KB  swizzled
    __shared__ float up_s[128 * 32];  // 16KB  linear (broadcast reads only)
    __shared__ float xs  [64 * 32];   //  8KB  swizzled (phase A)
    __shared__ float hls [64 * 32];   //  8KB  swizzled (phases A,C)
    __shared__ float Ah_s[64 * 32];   //  8KB  swizzled (phases B,D)
    __shared__ float T_s [64 * 32];   //  8KB  swizzled (phase D)
    __shared__ float Hs2 [2 * 1024];  //  8KB  linear (broadcast)
    __shared__ float W1s [1024];      //  4KB  linear (broadcast)
    __shared__ float W2s [512];       //  2KB  linear (broadcast)
    // total 110 KB -> exactly 1 block/CU

    const int tid = threadIdx.x;
    const int blk = blockIdx.x;
    const int bA = blk >> 7, nA = blk & 127;                     // roles A,C
    const int bB = blk >> 7, tB = (blk >> 1) & 63, mh = blk & 1; // roles B,D
    const int fg = tid >> 6;      // f-group 0..7 (4 floats)
    const int lt = tid & 63;      // lane: t (A,C) or local m (B,D)

    const float s0v = s[0], s1v = s[1], s2v = s[2], s3v = s[3];

    // ---------------- prologue staging (used across phases) ----------------
#pragma unroll
    for (int i = 0; i < 8; ++i) {                 // At [64][64]
        int p = tid + 512 * i;
        int r = p >> 6, c = p & 63;
        At_s[r * 64 + (swz(r, c >> 2) << 2) + (c & 3)] = At[p];
    }
#pragma unroll
    for (int i = 0; i < 4; ++i) {                 // As half-tile [64][128]
        int p = tid + 512 * i;
        int r = p >> 5, g = p & 31;
        float4 v = *(const float4*)(As + ((size_t)(mh * 64 + r)) * 128 + g * 4);
        *(float4*)&As_s[r * 128 + (swz(r, g) << 2)] = v;
    }
    if (tid < 256)      ((float4*)W1s)[tid]       = ((const float4*)W1)[tid];
    else if (tid < 384) ((float4*)W2s)[tid - 256] = ((const float4*)W2)[tid - 256];
#pragma unroll
    for (int i = 0; i < 4; ++i) {                 // Hsum[l] = sum_k H[l,k]
        int p = tid + 512 * i;                    // 0..2047
        const float* Hl = H + (p >> 10) * 4096;
        int rem = p & 1023;
        Hs2[p] = Hl[rem] + Hl[1024 + rem] + Hl[2048 + rem] + Hl[3072 + rem];
    }
    {                                             // x rows x[b, t*128+n, :]
        int tt = tid >> 3, c4 = tid & 7;
        float4 v = *(const float4*)(x + ((size_t)(bA * 8192 + tt * 128 + nA)) * 32 + c4 * 4);
        *(float4*)&xs[tt * 32 + (swz(tt, c4) << 2)] = v;
    }
    __syncthreads();

    // ---------------- phase A: input projection ----------------
    {
        float4 bv = *(const float4*)(b1 + fg * 4);
        float h0 = bv.x, h1 = bv.y, h2 = bv.z, h3 = bv.w;
#pragma unroll
        for (int k4 = 0; k4 < 8; ++k4) {
            float4 xv = *(const float4*)&xs[lt * 32 + (swz(lt, k4) << 2)];
            float4 w0 = *(const float4*)&W1s[(k4 * 4 + 0) * 32 + fg * 4];
            float4 w1 = *(const float4*)&W1s[(k4 * 4 + 1) * 32 + fg * 4];
            float4 w2 = *(const float4*)&W1s[(k4 * 4 + 2) * 32 + fg * 4];
            float4 w3 = *(const float4*)&W1s[(k4 * 4 + 3) * 32 + fg * 4];
            h0 += xv.x * w0.x + xv.y * w1.x + xv.z * w2.x + xv.w * w3.x;
            h1 += xv.x * w0.y + xv.y * w1.y + xv.z * w2.y + xv.w * w3.y;
            h2 += xv.x * w0.z + xv.y * w1.z + xv.z * w2.z + xv.w * w3.z;
            h3 += xv.x * w0.w + xv.y * w1.w + xv.z * w2.w + xv.w * w3.w;
        }
        float4 hv; hv.x = h0; hv.y = h1; hv.z = h2; hv.w = h3;
        *(float4*)&hls[lt * 32 + (swz(lt, fg) << 2)] = hv;
    }
    __syncthreads();

    // temporal mix macro body (reads hls/At_s, writes up/pp for (bA,nA))
#define TEMPORAL_MIX()                                                          \
    {                                                                           \
        float4 hv = *(const float4*)&hls[lt * 32 + (swz(lt, fg) << 2)];         \
        float w0 = 0.f, w1 = 0.f, w2 = 0.f, w3 = 0.f;                           \
        _Pragma("unroll")                                                       \
        for (int u4 = 0; u4 < 16; ++u4) {                                       \
            float4 av = *(const float4*)&At_s[lt * 64 + (swz(lt, u4) << 2)];    \
            float4 g0 = *(const float4*)&hls[(u4*4+0)*32 + (swz(u4*4+0, fg)<<2)]; \
            float4 g1 = *(const float4*)&hls[(u4*4+1)*32 + (swz(u4*4+1, fg)<<2)]; \
            float4 g2 = *(const float4*)&hls[(u4*4+2)*32 + (swz(u4*4+2, fg)<<2)]; \
            float4 g3 = *(const float4*)&hls[(u4*4+3)*32 + (swz(u4*4+3, fg)<<2)]; \
            w0 += av.x * g0.x + av.y * g1.x + av.z * g2.x + av.w * g3.x;        \
            w1 += av.x * g0.y + av.y * g1.y + av.z * g2.y + av.w * g3.y;        \
            w2 += av.x * g0.z + av.y * g1.z + av.z * g2.z + av.w * g3.z;        \
            w3 += av.x * g0.w + av.y * g1.w + av.z * g2.w + av.w * g3.w;        \
        }                                                                       \
        float4 uo, po;                                                          \
        uo.x = s1v * hv.x + s3v * w0;  po.x = s0v * hv.x + s2v * w0;            \
        uo.y = s1v * hv.y + s3v * w1;  po.y = s0v * hv.y + s2v * w1;            \
        uo.z = s1v * hv.z + s3v * w2;  po.z = s0v * hv.z + s2v * w2;            \
        uo.w = s1v * hv.w + s3v * w3;  po.w = s0v * hv.w + s2v * w3;            \
        size_t base = ((size_t)((bA * 64 + lt) * 128 + nA)) * 32 + fg * 4;      \
        *(float4*)(up + base) = uo;                                             \
        *(float4*)(pp + base) = po;                                             \
    }

    TEMPORAL_MIX();          // layer-0 temporal
    gbar(barcnt, 1 * NBLK);

    // spatial + filter macro (reads up/pp for (bB,tB,mh); LAYER l)
#define SPATIAL(l, LAST)                                                        \
    {                                                                           \
        const float* usrc = up + ((size_t)(bB * 64 + tB)) * 4096;               \
        ((float4*)up_s)[tid]       = ((const float4*)usrc)[tid];                \
        ((float4*)up_s)[tid + 512] = ((const float4*)usrc)[tid + 512];          \
        float4 pv = *(const float4*)(pp +                                       \
            ((size_t)((bB * 64 + tB) * 128 + mh * 64 + lt)) * 32 + fg * 4);     \
        __syncthreads();                                                        \
        float a0 = pv.x, a1 = pv.y, a2 = pv.z, a3 = pv.w;                       \
        _Pragma("unroll 8")                                                     \
        for (int n4 = 0; n4 < 32; ++n4) {                                       \
            float4 av = *(const float4*)&As_s[lt * 128 + (swz(lt, n4) << 2)];   \
            float4 u0 = *(const float4*)&up_s[(n4 * 4 + 0) * 32 + fg * 4];      \
            float4 u1 = *(const float4*)&up_s[(n4 * 4 + 1) * 32 + fg * 4];      \
            float4 u2 = *(const float4*)&up_s[(n4 * 4 + 2) * 32 + fg * 4];      \
            float4 u3 = *(const float4*)&up_s[(n4 * 4 + 3) * 32 + fg * 4];      \
            a0 += av.x * u0.x + av.y * u1.x + av.z * u2.x + av.w * u3.x;        \
            a1 += av.x * u0.y + av.y * u1.y + av.z * u2.y + av.w * u3.y;        \
            a2 += av.x * u0.z + av.y * u1.z + av.z * u2.z + av.w * u3.z;        \
            a3 += av.x * u0.w + av.y * u1.w + av.z * u2.w + av.w * u3.w;        \
        }                                                                       \
        { float4 t4; t4.x = a0; t4.y = a1; t4.z = a2; t4.w = a3;                \
          *(float4*)&Ah_s[lt * 32 + (swz(lt, fg) << 2)] = t4; }                 \
        __syncthreads();                                                        \
        float c0 = 0.f, c1 = 0.f, c2 = 0.f, c3 = 0.f;                           \
        _Pragma("unroll")                                                       \
        for (int k4 = 0; k4 < 8; ++k4) {                                        \
            float4 av = *(const float4*)&Ah_s[lt * 32 + (swz(lt, k4) << 2)];    \
            float4 q0 = *(const float4*)&Hs2[(l)*1024 + (k4*4+0)*32 + fg*4];    \
            float4 q1 = *(const float4*)&Hs2[(l)*1024 + (k4*4+1)*32 + fg*4];    \
            float4 q2 = *(const float4*)&Hs2[(l)*1024 + (k4*4+2)*32 + fg*4];    \
            float4 q3 = *(const float4*)&Hs2[(l)*1024 + (k4*4+3)*32 + fg*4];    \
            c0 += av.x * q0.x + av.y * q1.x + av.z * q2.x + av.w * q3.x;        \
            c1 += av.x * q0.y + av.y * q1.y + av.z * q2.y + av.w * q3.y;        \
            c2 += av.x * q0.z + av.y * q1.z + av.z * q2.z + av.w * q3.z;        \
            c3 += av.x * q0.w + av.y * q1.w + av.z * q2.w + av.w * q3.w;        \
        }                                                                       \
        c0 = tanhf(c0); c1 = tanhf(c1); c2 = tanhf(c2); c3 = tanhf(c3);         \
        if (!(LAST)) {                                                          \
            float4 o; o.x = c0; o.y = c1; o.z = c2; o.w = c3;                   \
            *(float4*)(hbuf +                                                   \
                (((size_t)(bB * 128 + mh * 64 + lt)) * 64 + tB) * 32 + fg * 4) = o; \
        } else {                                                                \
            float4 t4; t4.x = c0; t4.y = c1; t4.z = c2; t4.w = c3;              \
            *(float4*)&T_s[lt * 32 + (swz(lt, fg) << 2)] = t4;                  \
            __syncthreads();                                                    \
            const int fo = fg * 2;                                              \
            float o0 = b2[fo], o1 = b2[fo + 1];                                 \
            _Pragma("unroll")                                                   \
            for (int k4 = 0; k4 < 8; ++k4) {                                    \
                float4 tv = *(const float4*)&T_s[lt * 32 + (swz(lt, k4) << 2)]; \
                float2 v0 = *(const float2*)&W2s[(k4 * 4 + 0) * 16 + fo];       \
                float2 v1 = *(const float2*)&W2s[(k4 * 4 + 1) * 16 + fo];       \
                float2 v2 = *(const float2*)&W2s[(k4 * 4 + 2) * 16 + fo];       \
                float2 v3 = *(const float2*)&W2s[(k4 * 4 + 3) * 16 + fo];       \
                o0 += tv.x * v0.x + tv.y * v1.x + tv.z * v2.x + tv.w * v3.x;    \
                o1 += tv.x * v0.y + tv.y * v1.y + tv.z * v2.y + tv.w * v3.y;    \
            }                                                                   \
            float2 o2; o2.x = o0; o2.y = o1;                                    \
            *(float2*)(out +                                                    \
                ((size_t)((bB * 64 + tB) * 128 + mh * 64 + lt)) * 16 + fo) = o2; \
        }                                                                       \
    }

    SPATIAL(0, false);       // layer-0 spatial -> hbuf (n-major)
    gbar(barcnt, 2 * NBLK);

    // ---------------- phase C: temporal L1 (stage h row, contiguous 8KB) ----
    {
        int tt = tid >> 3, c4 = tid & 7;
        float4 v = *(const float4*)(hbuf + ((size_t)(bA * 128 + nA)) * 2048 + tt * 32 + c4 * 4);
        *(float4*)&hls[tt * 32 + (swz(tt, c4) << 2)] = v;
    }
    __syncthreads();
    TEMPORAL_MIX();          // layer-1 temporal
    gbar(barcnt, 3 * NBLK);

    SPATIAL(1, true);        // layer-1 spatial + fused output projection
}

// ---------------------------------------------------------------------------
extern "C" void kernel_launch(void* const* d_in, const int* in_sizes, int n_in,
                              void* d_out, int out_size, void* d_ws, size_t ws_size,
                              hipStream_t stream)
{
    const float* x   = (const float*)d_in[0];
    const float* At  = (const float*)d_in[1];
    const float* As  = (const float*)d_in[2];
    const float* s   = (const float*)d_in[3];
    const float* H   = (const float*)d_in[4];
    const float* W1  = (const float*)d_in[5];
    const float* b1  = (const float*)d_in[6];
    const float* W2  = (const float*)d_in[7];
    const float* b2  = (const float*)d_in[8];
    float* out = (float*)d_out;

    float*    up     = (float*)d_ws;           // [2][64][128][32]  524288 floats
    float*    pp     = up + 524288;            // same layout
    float*    hbuf   = pp + 524288;            // [2][128][64][32]  n-major
    unsigned* barcnt = (unsigned*)(hbuf + 524288);

    // Deterministic barrier state every call (graph-capturable memset node).
    hipMemsetAsync(barcnt, 0, sizeof(unsigned), stream);

    k_fused<<<NBLK, 512, 0, stream>>>(x, At, As, s, H, W1, b1, W2, b2,
                                      up, pp, hbuf, barcnt, out);
}

// Round 8
// 89.205 us; speedup vs baseline: 3.7735x; 3.7735x over previous
//
#include <hip/hip_runtime.h>

// GTCNN fused persistent kernel.
// Math (verified rounds 2-4): Adj = s0 I + s1 (I⊗As) + s2 (At⊗I) + s3 (At⊗As)
//   => per layer: w = temporal mix (At over t);  u = s1 h + s3 w;  p = s0 h + s2 w
//      Ah = p + As ⊛ u (spatial over n);  h' = tanh(Ah @ Hsum[l]),  Hsum = Σ_k H[l,k]
// Shapes: B=2, T=64, N=128, F=32, out F=16.
//
// Single kernel, 256 blocks (=CU count; 110KB LDS -> 1 block/CU => co-resident),
// 3 device-scope grid barriers between the 4 phases:
//   A: proj(x@W1+b1) + temporal L0   (block role (b,n))
//   B: spatial + filter L0           (block role (b,t,mh))
//   C: temporal L1                   (block role (b,n))
//   D: spatial + filter L1 + out-proj(W2,b2)
//
// Round-8 barrier redesign (round 7 was 340us, ~97% stalled in the barrier):
//   - ONE agent release fence + ONE agent acquire fence per block per barrier
//     (thread 0 only). Round 7 had 512 threads x 2 threadfences each -> L2
//     cache-maintenance storm.
//   - RELAXED atomics for add + poll (round 7 polled with ACQUIRE = cache ops
//     per iteration).
//   - s_sleep(16) poll period to decongest the counter cacheline.
// Counter memset to 0 on the stream each call; targets explicit phase*NBLK.

#define NBLK 256

__device__ __forceinline__ int swz(int row, int g) { return g ^ (row & 7); }

// Grid barrier: counter starts at 0 (host memset); phase p waits for p*NBLK.
// Bounded spin => degrades to wrong-output (diagnosable) instead of hang.
__device__ __forceinline__ void gbar(unsigned* cnt, unsigned tgt) {
    __syncthreads();   // all waves' stores issued+complete (vmcnt drained)
    if (threadIdx.x == 0) {
        __builtin_amdgcn_fence(__ATOMIC_RELEASE, "agent");   // 1 L2-writeback/block
        __hip_atomic_fetch_add(cnt, 1u, __ATOMIC_RELAXED,
                               __HIP_MEMORY_SCOPE_AGENT);
        int guard = 1 << 22;
        while (__hip_atomic_load(cnt, __ATOMIC_RELAXED,
                                 __HIP_MEMORY_SCOPE_AGENT) < tgt && --guard)
            __builtin_amdgcn_s_sleep(16);
        __builtin_amdgcn_fence(__ATOMIC_ACQUIRE, "agent");   // 1 L1/L2-inv/block
    }
    __syncthreads();   // other waves held until fence done (same CU -> same L1)
}

__global__ __launch_bounds__(512) void k_fused(
    const float* __restrict__ x,  const float* __restrict__ At,
    const float* __restrict__ As, const float* __restrict__ s,
    const float* __restrict__ H,  const float* __restrict__ W1,
    const float* __restrict__ b1, const float* __restrict__ W2,
    const float* __restrict__ b2,
    float* __restrict__ up, float* __restrict__ pp, float* __restrict__ hbuf,
    unsigned* __restrict__ barcnt, float* __restrict__ out)
{
    __shared__ float As_s[64 * 128];  // 32KB  half-tile rows As[mh*64 + r], swizzled
    __shared__ float At_s[64 * 64];   // 16KB  swizzled
    __shared__ float up_s[128 * 32];  // 16KB  linear (broadcast reads only)
    __shared__ float xs  [64 * 32];   //  8KB  swizzled (phase A)
    __shared__ float hls [64 * 32];   //  8KB  swizzled (phases A,C)
    __shared__ float Ah_s[64 * 32];   //  8KB  swizzled (phases B,D)
    __shared__ float T_s [64 * 32];   //  8KB  swizzled (phase D)
    __shared__ float Hs2 [2 * 1024];  //  8KB  linear (broadcast)
    __shared__ float W1s [1024];      //  4KB  linear (broadcast)
    __shared__ float W2s [512];       //  2KB  linear (broadcast)
    // total 110 KB -> exactly 1 block/CU

    const int tid = threadIdx.x;
    const int blk = blockIdx.x;
    const int bA = blk >> 7, nA = blk & 127;                     // roles A,C
    const int bB = blk >> 7, tB = (blk >> 1) & 63, mh = blk & 1; // roles B,D
    const int fg = tid >> 6;      // f-group 0..7 (4 floats)
    const int lt = tid & 63;      // lane: t (A,C) or local m (B,D)

    const float s0v = s[0], s1v = s[1], s2v = s[2], s3v = s[3];

    // ---------------- prologue staging (used across phases) ----------------
#pragma unroll
    for (int i = 0; i < 8; ++i) {                 // At [64][64]
        int p = tid + 512 * i;
        int r = p >> 6, c = p & 63;
        At_s[r * 64 + (swz(r, c >> 2) << 2) + (c & 3)] = At[p];
    }
#pragma unroll
    for (int i = 0; i < 4; ++i) {                 // As half-tile [64][128]
        int p = tid + 512 * i;
        int r = p >> 5, g = p & 31;
        float4 v = *(const float4*)(As + ((size_t)(mh * 64 + r)) * 128 + g * 4);
        *(float4*)&As_s[r * 128 + (swz(r, g) << 2)] = v;
    }
    if (tid < 256)      ((float4*)W1s)[tid]       = ((const float4*)W1)[tid];
    else if (tid < 384) ((float4*)W2s)[tid - 256] = ((const float4*)W2)[tid - 256];
#pragma unroll
    for (int i = 0; i < 4; ++i) {                 // Hsum[l] = sum_k H[l,k]
        int p = tid + 512 * i;                    // 0..2047
        const float* Hl = H + (p >> 10) * 4096;
        int rem = p & 1023;
        Hs2[p] = Hl[rem] + Hl[1024 + rem] + Hl[2048 + rem] + Hl[3072 + rem];
    }
    {                                             // x rows x[b, t*128+n, :]
        int tt = tid >> 3, c4 = tid & 7;
        float4 v = *(const float4*)(x + ((size_t)(bA * 8192 + tt * 128 + nA)) * 32 + c4 * 4);
        *(float4*)&xs[tt * 32 + (swz(tt, c4) << 2)] = v;
    }
    __syncthreads();

    // ---------------- phase A: input projection ----------------
    {
        float4 bv = *(const float4*)(b1 + fg * 4);
        float h0 = bv.x, h1 = bv.y, h2 = bv.z, h3 = bv.w;
#pragma unroll
        for (int k4 = 0; k4 < 8; ++k4) {
            float4 xv = *(const float4*)&xs[lt * 32 + (swz(lt, k4) << 2)];
            float4 w0 = *(const float4*)&W1s[(k4 * 4 + 0) * 32 + fg * 4];
            float4 w1 = *(const float4*)&W1s[(k4 * 4 + 1) * 32 + fg * 4];
            float4 w2 = *(const float4*)&W1s[(k4 * 4 + 2) * 32 + fg * 4];
            float4 w3 = *(const float4*)&W1s[(k4 * 4 + 3) * 32 + fg * 4];
            h0 += xv.x * w0.x + xv.y * w1.x + xv.z * w2.x + xv.w * w3.x;
            h1 += xv.x * w0.y + xv.y * w1.y + xv.z * w2.y + xv.w * w3.y;
            h2 += xv.x * w0.z + xv.y * w1.z + xv.z * w2.z + xv.w * w3.z;
            h3 += xv.x * w0.w + xv.y * w1.w + xv.z * w2.w + xv.w * w3.w;
        }
        float4 hv; hv.x = h0; hv.y = h1; hv.z = h2; hv.w = h3;
        *(float4*)&hls[lt * 32 + (swz(lt, fg) << 2)] = hv;
    }
    __syncthreads();

    // temporal mix macro body (reads hls/At_s, writes up/pp for (bA,nA))
#define TEMPORAL_MIX()                                                          \
    {                                                                           \
        float4 hv = *(const float4*)&hls[lt * 32 + (swz(lt, fg) << 2)];         \
        float w0 = 0.f, w1 = 0.f, w2 = 0.f, w3 = 0.f;                           \
        _Pragma("unroll")                                                       \
        for (int u4 = 0; u4 < 16; ++u4) {                                       \
            float4 av = *(const float4*)&At_s[lt * 64 + (swz(lt, u4) << 2)];    \
            float4 g0 = *(const float4*)&hls[(u4*4+0)*32 + (swz(u4*4+0, fg)<<2)]; \
            float4 g1 = *(const float4*)&hls[(u4*4+1)*32 + (swz(u4*4+1, fg)<<2)]; \
            float4 g2 = *(const float4*)&hls[(u4*4+2)*32 + (swz(u4*4+2, fg)<<2)]; \
            float4 g3 = *(const float4*)&hls[(u4*4+3)*32 + (swz(u4*4+3, fg)<<2)]; \
            w0 += av.x * g0.x + av.y * g1.x + av.z * g2.x + av.w * g3.x;        \
            w1 += av.x * g0.y + av.y * g1.y + av.z * g2.y + av.w * g3.y;        \
            w2 += av.x * g0.z + av.y * g1.z + av.z * g2.z + av.w * g3.z;        \
            w3 += av.x * g0.w + av.y * g1.w + av.z * g2.w + av.w * g3.w;        \
        }                                                                       \
        float4 uo, po;                                                          \
        uo.x = s1v * hv.x + s3v * w0;  po.x = s0v * hv.x + s2v * w0;            \
        uo.y = s1v * hv.y + s3v * w1;  po.y = s0v * hv.y + s2v * w1;            \
        uo.z = s1v * hv.z + s3v * w2;  po.z = s0v * hv.z + s2v * w2;            \
        uo.w = s1v * hv.w + s3v * w3;  po.w = s0v * hv.w + s2v * w3;            \
        size_t base = ((size_t)((bA * 64 + lt) * 128 + nA)) * 32 + fg * 4;      \
        *(float4*)(up + base) = uo;                                             \
        *(float4*)(pp + base) = po;                                             \
    }

    TEMPORAL_MIX();          // layer-0 temporal
    gbar(barcnt, 1 * NBLK);

    // spatial + filter macro (reads up/pp for (bB,tB,mh); LAYER l)
#define SPATIAL(l, LAST)                                                        \
    {                                                                           \
        const float* usrc = up + ((size_t)(bB * 64 + tB)) * 4096;               \
        ((float4*)up_s)[tid]       = ((const float4*)usrc)[tid];                \
        ((float4*)up_s)[tid + 512] = ((const float4*)usrc)[tid + 512];          \
        float4 pv = *(const float4*)(pp +                                       \
            ((size_t)((bB * 64 + tB) * 128 + mh * 64 + lt)) * 32 + fg * 4);     \
        __syncthreads();                                                        \
        float a0 = pv.x, a1 = pv.y, a2 = pv.z, a3 = pv.w;                       \
        _Pragma("unroll 8")                                                     \
        for (int n4 = 0; n4 < 32; ++n4) {                                       \
            float4 av = *(const float4*)&As_s[lt * 128 + (swz(lt, n4) << 2)];   \
            float4 u0 = *(const float4*)&up_s[(n4 * 4 + 0) * 32 + fg * 4];      \
            float4 u1 = *(const float4*)&up_s[(n4 * 4 + 1) * 32 + fg * 4];      \
            float4 u2 = *(const float4*)&up_s[(n4 * 4 + 2) * 32 + fg * 4];      \
            float4 u3 = *(const float4*)&up_s[(n4 * 4 + 3) * 32 + fg * 4];      \
            a0 += av.x * u0.x + av.y * u1.x + av.z * u2.x + av.w * u3.x;        \
            a1 += av.x * u0.y + av.y * u1.y + av.z * u2.y + av.w * u3.y;        \
            a2 += av.x * u0.z + av.y * u1.z + av.z * u2.z + av.w * u3.z;        \
            a3 += av.x * u0.w + av.y * u1.w + av.z * u2.w + av.w * u3.w;        \
        }                                                                       \
        { float4 t4; t4.x = a0; t4.y = a1; t4.z = a2; t4.w = a3;                \
          *(float4*)&Ah_s[lt * 32 + (swz(lt, fg) << 2)] = t4; }                 \
        __syncthreads();                                                        \
        float c0 = 0.f, c1 = 0.f, c2 = 0.f, c3 = 0.f;                           \
        _Pragma("unroll")                                                       \
        for (int k4 = 0; k4 < 8; ++k4) {                                        \
            float4 av = *(const float4*)&Ah_s[lt * 32 + (swz(lt, k4) << 2)];    \
            float4 q0 = *(const float4*)&Hs2[(l)*1024 + (k4*4+0)*32 + fg*4];    \
            float4 q1 = *(const float4*)&Hs2[(l)*1024 + (k4*4+1)*32 + fg*4];    \
            float4 q2 = *(const float4*)&Hs2[(l)*1024 + (k4*4+2)*32 + fg*4];    \
            float4 q3 = *(const float4*)&Hs2[(l)*1024 + (k4*4+3)*32 + fg*4];    \
            c0 += av.x * q0.x + av.y * q1.x + av.z * q2.x + av.w * q3.x;        \
            c1 += av.x * q0.y + av.y * q1.y + av.z * q2.y + av.w * q3.y;        \
            c2 += av.x * q0.z + av.y * q1.z + av.z * q2.z + av.w * q3.z;        \
            c3 += av.x * q0.w + av.y * q1.w + av.z * q2.w + av.w * q3.w;        \
        }                                                                       \
        c0 = tanhf(c0); c1 = tanhf(c1); c2 = tanhf(c2); c3 = tanhf(c3);         \
        if (!(LAST)) {                                                          \
            float4 o; o.x = c0; o.y = c1; o.z = c2; o.w = c3;                   \
            *(float4*)(hbuf +                                                   \
                (((size_t)(bB * 128 + mh * 64 + lt)) * 64 + tB) * 32 + fg * 4) = o; \
        } else {                                                                \
            float4 t4; t4.x = c0; t4.y = c1; t4.z = c2; t4.w = c3;              \
            *(float4*)&T_s[lt * 32 + (swz(lt, fg) << 2)] = t4;                  \
            __syncthreads();                                                    \
            const int fo = fg * 2;                                              \
            float o0 = b2[fo], o1 = b2[fo + 1];                                 \
            _Pragma("unroll")                                                   \
            for (int k4 = 0; k4 < 8; ++k4) {                                    \
                float4 tv = *(const float4*)&T_s[lt * 32 + (swz(lt, k4) << 2)]; \
                float2 v0 = *(const float2*)&W2s[(k4 * 4 + 0) * 16 + fo];       \
                float2 v1 = *(const float2*)&W2s[(k4 * 4 + 1) * 16 + fo];       \
                float2 v2 = *(const float2*)&W2s[(k4 * 4 + 2) * 16 + fo];       \
                float2 v3 = *(const float2*)&W2s[(k4 * 4 + 3) * 16 + fo];       \
                o0 += tv.x * v0.x + tv.y * v1.x + tv.z * v2.x + tv.w * v3.x;    \
                o1 += tv.x * v0.y + tv.y * v1.y + tv.z * v2.y + tv.w * v3.y;    \
            }                                                                   \
            float2 o2; o2.x = o0; o2.y = o1;                                    \
            *(float2*)(out +                                                    \
                ((size_t)((bB * 64 + tB) * 128 + mh * 64 + lt)) * 16 + fo) = o2; \
        }                                                                       \
    }

    SPATIAL(0, false);       // layer-0 spatial -> hbuf (n-major)
    gbar(barcnt, 2 * NBLK);

    // ---------------- phase C: temporal L1 (stage h row, contiguous 8KB) ----
    {
        int tt = tid >> 3, c4 = tid & 7;
        float4 v = *(const float4*)(hbuf + ((size_t)(bA * 128 + nA)) * 2048 + tt * 32 + c4 * 4);
        *(float4*)&hls[tt * 32 + (swz(tt, c4) << 2)] = v;
    }
    __syncthreads();
    TEMPORAL_MIX();          // layer-1 temporal
    gbar(barcnt, 3 * NBLK);

    SPATIAL(1, true);        // layer-1 spatial + fused output projection
}

// ---------------------------------------------------------------------------
extern "C" void kernel_launch(void* const* d_in, const int* in_sizes, int n_in,
                              void* d_out, int out_size, void* d_ws, size_t ws_size,
                              hipStream_t stream)
{
    const float* x   = (const float*)d_in[0];
    const float* At  = (const float*)d_in[1];
    const float* As  = (const float*)d_in[2];
    const float* s   = (const float*)d_in[3];
    const float* H   = (const float*)d_in[4];
    const float* W1  = (const float*)d_in[5];
    const float* b1  = (const float*)d_in[6];
    const float* W2  = (const float*)d_in[7];
    const float* b2  = (const float*)d_in[8];
    float* out = (float*)d_out;

    float*    up     = (float*)d_ws;           // [2][64][128][32]  524288 floats
    float*    pp     = up + 524288;            // same layout
    float*    hbuf   = pp + 524288;            // [2][128][64][32]  n-major
    unsigned* barcnt = (unsigned*)(hbuf + 524288);

    // Deterministic barrier state every call (graph-capturable memset node).
    hipMemsetAsync(barcnt, 0, sizeof(unsigned), stream);

    k_fused<<<NBLK, 512, 0, stream>>>(x, At, As, s, H, W1, b1, W2, b2,
                                      up, pp, hbuf, barcnt, out);
}

// Round 9
// 32.790 us; speedup vs baseline: 10.2660x; 2.7205x over previous
//
#include <hip/hip_runtime.h>

// GTCNN — 4-kernel structure (kernel boundaries ARE the grid barriers; round 8
// proved software barriers cost ~25us each vs ~3us for a launch boundary).
// Math (verified rounds 2-8): Adj = s0 I + s1 (I⊗As) + s2 (At⊗I) + s3 (At⊗As)
//   per layer: w[t] = sum_u At[t,u] h[u]  (temporal, per (b,n) column)
//              u = s1 h + s3 w ; p = s0 h + s2 w
//              Ah[m] = p[m] + sum_n As[m,n] u[n]  (spatial, per (b,t))
//              h' = tanh(Ah @ Hsum[l]),  Hsum[l] = sum_k H[l,k]
// Kernels: T0 = proj(x@W1+b1)+temporal ; S0 = spatial+filter -> hbuf (n-major)
//          T1 = temporal ; S1 = spatial+filter+out-proj(W2,b2)
//
// LDS discipline (HW-proven in rounds 6-8, absmax 4.88e-4):
//   lane-distinct tiles -> XOR group swizzle  g' = g ^ (row&7)  (b128
//   conflict-ideal: lanes 0..7 cover all 8 bank-groups);
//   wave-uniform operands -> linear LDS, broadcast reads (free).
// Layouts: x[B][T*N][32]; up/pp[B][T][N][32]; hbuf[B][N][T][32] (n-major so
// T1's per-(b,n) read is one contiguous 8KB row); out[B][T*N][16].

__device__ __forceinline__ int swz(int row, int g) { return g ^ (row & 7); }

// ---------------------------------------------------------------------------
// Temporal kernel. grid = B*N = 256, 512 threads.
// wave fg = tid>>6 (4-float f-chunk), lane lt = tid&63 (time step).
// ---------------------------------------------------------------------------
template<bool PROJ>
__global__ __launch_bounds__(512) void k_temporal(
    const float* __restrict__ src,     // PROJ ? x : hbuf (n-major)
    const float* __restrict__ At,
    const float* __restrict__ W1, const float* __restrict__ b1,
    const float* __restrict__ s,
    float* __restrict__ up, float* __restrict__ pp)
{
    __shared__ float At_s[64 * 64];   // swizzled, b128 reads (4 u per DS op)
    __shared__ float xs  [64 * 32];   // swizzled (PROJ only)
    __shared__ float hls [64 * 32];   // swizzled writes, broadcast reads
    __shared__ float W1s [1024];      // linear (broadcast reads, PROJ only)

    const int tid = threadIdx.x;
    const int b   = blockIdx.x >> 7;
    const int n   = blockIdx.x & 127;
    const int fg  = tid >> 6;
    const int lt  = tid & 63;

    const float s0v = s[0], s1v = s[1], s2v = s[2], s3v = s[3];

    // stage At [64][64] -> swizzled groups (scalar writes, 2-way = free)
#pragma unroll
    for (int i = 0; i < 8; ++i) {
        int p = tid + 512 * i;
        int r = p >> 6, c = p & 63;
        At_s[r * 64 + (swz(r, c >> 2) << 2) + (c & 3)] = At[p];
    }

    if (PROJ) {
        // stage x rows x[b, t*128+n, :] -> xs (swizzled)
        {
            int tt = tid >> 3, c4 = tid & 7;
            float4 v = *(const float4*)(src + ((size_t)(b * 8192 + tt * 128 + n)) * 32 + c4 * 4);
            *(float4*)&xs[tt * 32 + (swz(tt, c4) << 2)] = v;
        }
        if (tid < 256) ((float4*)W1s)[tid] = ((const float4*)W1)[tid];
        __syncthreads();
        // h = x @ W1 + b1  (xs b128 lane-distinct; W1s broadcast)
        float4 bv = *(const float4*)(b1 + fg * 4);
        float h0 = bv.x, h1 = bv.y, h2 = bv.z, h3 = bv.w;
#pragma unroll
        for (int k4 = 0; k4 < 8; ++k4) {
            float4 xv = *(const float4*)&xs[lt * 32 + (swz(lt, k4) << 2)];
            float4 w0 = *(const float4*)&W1s[(k4 * 4 + 0) * 32 + fg * 4];
            float4 w1 = *(const float4*)&W1s[(k4 * 4 + 1) * 32 + fg * 4];
            float4 w2 = *(const float4*)&W1s[(k4 * 4 + 2) * 32 + fg * 4];
            float4 w3 = *(const float4*)&W1s[(k4 * 4 + 3) * 32 + fg * 4];
            h0 += xv.x * w0.x + xv.y * w1.x + xv.z * w2.x + xv.w * w3.x;
            h1 += xv.x * w0.y + xv.y * w1.y + xv.z * w2.y + xv.w * w3.y;
            h2 += xv.x * w0.z + xv.y * w1.z + xv.z * w2.z + xv.w * w3.z;
            h3 += xv.x * w0.w + xv.y * w1.w + xv.z * w2.w + xv.w * w3.w;
        }
        float4 hv; hv.x = h0; hv.y = h1; hv.z = h2; hv.w = h3;
        *(float4*)&hls[lt * 32 + (swz(lt, fg) << 2)] = hv;
        __syncthreads();
    } else {
        // stage h row (b,n): contiguous 8KB -> hls (swizzled)
        {
            int tt = tid >> 3, c4 = tid & 7;
            float4 v = *(const float4*)(src + ((size_t)(b * 128 + n)) * 2048 + tt * 32 + c4 * 4);
            *(float4*)&hls[tt * 32 + (swz(tt, c4) << 2)] = v;
        }
        __syncthreads();
    }

    // temporal mix: At b128 lane-distinct (1 DS / 4 u's) + 4 broadcast h reads
    float4 hv = *(const float4*)&hls[lt * 32 + (swz(lt, fg) << 2)];
    float w0 = 0.f, w1 = 0.f, w2 = 0.f, w3 = 0.f;
#pragma unroll
    for (int u4 = 0; u4 < 16; ++u4) {
        float4 av = *(const float4*)&At_s[lt * 64 + (swz(lt, u4) << 2)];
        float4 g0 = *(const float4*)&hls[(u4 * 4 + 0) * 32 + (swz(u4 * 4 + 0, fg) << 2)];
        float4 g1 = *(const float4*)&hls[(u4 * 4 + 1) * 32 + (swz(u4 * 4 + 1, fg) << 2)];
        float4 g2 = *(const float4*)&hls[(u4 * 4 + 2) * 32 + (swz(u4 * 4 + 2, fg) << 2)];
        float4 g3 = *(const float4*)&hls[(u4 * 4 + 3) * 32 + (swz(u4 * 4 + 3, fg) << 2)];
        w0 += av.x * g0.x + av.y * g1.x + av.z * g2.x + av.w * g3.x;
        w1 += av.x * g0.y + av.y * g1.y + av.z * g2.y + av.w * g3.y;
        w2 += av.x * g0.z + av.y * g1.z + av.z * g2.z + av.w * g3.z;
        w3 += av.x * g0.w + av.y * g1.w + av.z * g2.w + av.w * g3.w;
    }
    float4 uo, po;
    uo.x = s1v * hv.x + s3v * w0;  po.x = s0v * hv.x + s2v * w0;
    uo.y = s1v * hv.y + s3v * w1;  po.y = s0v * hv.y + s2v * w1;
    uo.z = s1v * hv.z + s3v * w2;  po.z = s0v * hv.z + s2v * w2;
    uo.w = s1v * hv.w + s3v * w3;  po.w = s0v * hv.w + s2v * w3;
    size_t base = ((size_t)((b * 64 + lt) * 128 + n)) * 32 + fg * 4;
    *(float4*)(up + base) = uo;
    *(float4*)(pp + base) = po;
}

// ---------------------------------------------------------------------------
// Spatial kernel. grid = B*T*2 = 256, 512 threads.
// wave fg = tid>>6, lane m = tid&63 (local spatial row of half mh).
// ---------------------------------------------------------------------------
template<bool LAST>
__global__ __launch_bounds__(512) void k_spatial(
    const float* __restrict__ up, const float* __restrict__ pp,
    const float* __restrict__ As, const float* __restrict__ H, int layer,
    const float* __restrict__ W2, const float* __restrict__ b2,
    float* __restrict__ hout, float* __restrict__ out)
{
    __shared__ float As_s[64 * 128];  // 32KB swizzled (b128 lane-distinct)
    __shared__ float up_s[128 * 32];  // 16KB linear (broadcast reads)
    __shared__ float Ah_s[64 * 32];   //  8KB swizzled
    __shared__ float T_s [64 * 32];   //  8KB swizzled (LAST only)
    __shared__ float Hs  [1024];      //  4KB linear (broadcast)
    __shared__ float W2s [512];       //  2KB linear (broadcast, LAST only)

    const int tid = threadIdx.x;
    const int b   = blockIdx.x >> 7;
    const int t   = (blockIdx.x >> 1) & 63;
    const int mh  = blockIdx.x & 1;
    const int fg  = tid >> 6;
    const int m   = tid & 63;

    // stage As half-tile [64][128] swizzled
#pragma unroll
    for (int i = 0; i < 4; ++i) {
        int p = tid + 512 * i;
        int r = p >> 5, g = p & 31;
        float4 v = *(const float4*)(As + ((size_t)(mh * 64 + r)) * 128 + g * 4);
        *(float4*)&As_s[r * 128 + (swz(r, g) << 2)] = v;
    }
    // stage up tile [128][32] linear (coalesced)
    {
        const float* usrc = up + ((size_t)(b * 64 + t)) * 4096;
        ((float4*)up_s)[tid]       = ((const float4*)usrc)[tid];
        ((float4*)up_s)[tid + 512] = ((const float4*)usrc)[tid + 512];
    }
    // Hsum for this layer
    {
        const float* Hl = H + layer * 4096;
#pragma unroll
        for (int i = 0; i < 2; ++i) {
            int p = tid + 512 * i;
            Hs[p] = Hl[p] + Hl[1024 + p] + Hl[2048 + p] + Hl[3072 + p];
        }
    }
    if (LAST && tid < 128) ((float4*)W2s)[tid] = ((const float4*)W2)[tid];
    // acc init from pp (lane-distinct; overlaps staging)
    float4 pv = *(const float4*)(pp + ((size_t)((b * 64 + t) * 128 + mh * 64 + m)) * 32 + fg * 4);
    float a0 = pv.x, a1 = pv.y, a2 = pv.z, a3 = pv.w;
    __syncthreads();

    // spatial mix: As b128 lane-distinct swizzled + 4 broadcast up reads
#pragma unroll 8
    for (int n4 = 0; n4 < 32; ++n4) {
        float4 av = *(const float4*)&As_s[m * 128 + (swz(m, n4) << 2)];
        float4 u0 = *(const float4*)&up_s[(n4 * 4 + 0) * 32 + fg * 4];
        float4 u1 = *(const float4*)&up_s[(n4 * 4 + 1) * 32 + fg * 4];
        float4 u2 = *(const float4*)&up_s[(n4 * 4 + 2) * 32 + fg * 4];
        float4 u3 = *(const float4*)&up_s[(n4 * 4 + 3) * 32 + fg * 4];
        a0 += av.x * u0.x + av.y * u1.x + av.z * u2.x + av.w * u3.x;
        a1 += av.x * u0.y + av.y * u1.y + av.z * u2.y + av.w * u3.y;
        a2 += av.x * u0.z + av.y * u1.z + av.z * u2.z + av.w * u3.z;
        a3 += av.x * u0.w + av.y * u1.w + av.z * u2.w + av.w * u3.w;
    }
    {
        float4 t4; t4.x = a0; t4.y = a1; t4.z = a2; t4.w = a3;
        *(float4*)&Ah_s[m * 32 + (swz(m, fg) << 2)] = t4;
    }
    __syncthreads();

    // graph filter + tanh: Ah b128 lane-distinct + Hs broadcast
    float c0 = 0.f, c1 = 0.f, c2 = 0.f, c3 = 0.f;
#pragma unroll
    for (int k4 = 0; k4 < 8; ++k4) {
        float4 av = *(const float4*)&Ah_s[m * 32 + (swz(m, k4) << 2)];
        float4 q0 = *(const float4*)&Hs[(k4 * 4 + 0) * 32 + fg * 4];
        float4 q1 = *(const float4*)&Hs[(k4 * 4 + 1) * 32 + fg * 4];
        float4 q2 = *(const float4*)&Hs[(k4 * 4 + 2) * 32 + fg * 4];
        float4 q3 = *(const float4*)&Hs[(k4 * 4 + 3) * 32 + fg * 4];
        c0 += av.x * q0.x + av.y * q1.x + av.z * q2.x + av.w * q3.x;
        c1 += av.x * q0.y + av.y * q1.y + av.z * q2.y + av.w * q3.y;
        c2 += av.x * q0.z + av.y * q1.z + av.z * q2.z + av.w * q3.z;
        c3 += av.x * q0.w + av.y * q1.w + av.z * q2.w + av.w * q3.w;
    }
    c0 = tanhf(c0); c1 = tanhf(c1); c2 = tanhf(c2); c3 = tanhf(c3);

    if (!LAST) {
        float4 o; o.x = c0; o.y = c1; o.z = c2; o.w = c3;
        // h stored n-major: [b][nglob][t][f]
        *(float4*)(hout + (((size_t)(b * 128 + mh * 64 + m)) * 64 + t) * 32 + fg * 4) = o;
    } else {
        float4 t4; t4.x = c0; t4.y = c1; t4.z = c2; t4.w = c3;
        *(float4*)&T_s[m * 32 + (swz(m, fg) << 2)] = t4;
        __syncthreads();
        // fused output projection: wave fg covers fo = {fg*2, fg*2+1}
        const int fo = fg * 2;
        float o0 = b2[fo], o1 = b2[fo + 1];
#pragma unroll
        for (int k4 = 0; k4 < 8; ++k4) {
            float4 tv = *(const float4*)&T_s[m * 32 + (swz(m, k4) << 2)];
            float2 v0 = *(const float2*)&W2s[(k4 * 4 + 0) * 16 + fo];
            float2 v1 = *(const float2*)&W2s[(k4 * 4 + 1) * 16 + fo];
            float2 v2 = *(const float2*)&W2s[(k4 * 4 + 2) * 16 + fo];
            float2 v3 = *(const float2*)&W2s[(k4 * 4 + 3) * 16 + fo];
            o0 += tv.x * v0.x + tv.y * v1.x + tv.z * v2.x + tv.w * v3.x;
            o1 += tv.x * v0.y + tv.y * v1.y + tv.z * v2.y + tv.w * v3.y;
        }
        float2 o2; o2.x = o0; o2.y = o1;
        *(float2*)(out + ((size_t)((b * 64 + t) * 128 + mh * 64 + m)) * 16 + fo) = o2;
    }
}

// ---------------------------------------------------------------------------
extern "C" void kernel_launch(void* const* d_in, const int* in_sizes, int n_in,
                              void* d_out, int out_size, void* d_ws, size_t ws_size,
                              hipStream_t stream)
{
    const float* x   = (const float*)d_in[0];
    const float* At  = (const float*)d_in[1];
    const float* As  = (const float*)d_in[2];
    const float* s   = (const float*)d_in[3];
    const float* H   = (const float*)d_in[4];
    const float* W1  = (const float*)d_in[5];
    const float* b1  = (const float*)d_in[6];
    const float* W2  = (const float*)d_in[7];
    const float* b2  = (const float*)d_in[8];
    float* out = (float*)d_out;

    float* up   = (float*)d_ws;            // [2][64][128][32]  524288 floats
    float* pp   = up + 524288;             // same layout
    float* hbuf = pp + 524288;             // [2][128][64][32]  n-major

    k_temporal<true ><<<256, 512, 0, stream>>>(x,    At, W1, b1, s, up, pp);
    k_spatial <false><<<256, 512, 0, stream>>>(up, pp, As, H, 0, W2, b2, hbuf, out);
    k_temporal<false><<<256, 512, 0, stream>>>(hbuf, At, W1, b1, s, up, pp);
    k_spatial <true ><<<256, 512, 0, stream>>>(up, pp, As, H, 1, W2, b2, hbuf, out);
}